// Round 3
// baseline (8729.414 us; speedup 1.0000x reference)
//
#include <hip/hip_runtime.h>
#include <math.h>

#define TT   2048
#define DD   1024
#define HH   16
#define HSS  64
#define EE   8
#define KTOP 2
#define LL   2
#define CAPP 512
#define NN   2048
#define DFF  4096
#define NK   (NN*KTOP)
#define HALF 32

// ---------------- embedding: x = tok_emb[ids] + pos_emb ----------------
__global__ __launch_bounds__(256) void embed_kernel(const int* __restrict__ ids,
                                                    const float* __restrict__ tok,
                                                    const float* __restrict__ pos,
                                                    float* __restrict__ x) {
  int t = blockIdx.x, tid = threadIdx.x;
  int id = ids[t];
  float4 a = ((const float4*)(tok + (long long)id * DD))[tid];
  float4 b = ((const float4*)(pos + (long long)t * DD))[tid];
  float4 r;
  r.x = a.x + b.x; r.y = a.y + b.y; r.z = a.z + b.z; r.w = a.w + b.w;
  ((float4*)(x + (long long)t * DD))[tid] = r;
}

// ---------------- RoPE sin/cos table (double precision) ----------------
__global__ __launch_bounds__(256) void sincos_kernel(float* __restrict__ st, float* __restrict__ ct) {
  int idx = blockIdx.x * 256 + threadIdx.x;      // T*HALF = 65536
  int t = idx >> 5, i = idx & 31;
  double div = exp(-(double)(2 * i) * (9.210340371976184 / 64.0)); // ln(10000)
  double a = (double)t * div;
  st[idx] = (float)sin(a);
  ct[idx] = (float)cos(a);
}

// ---------------- layernorm (row per block) ----------------
__global__ __launch_bounds__(256) void ln_kernel(const float* __restrict__ in, float* __restrict__ out,
                                                 const float* __restrict__ w, const float* __restrict__ b) {
  int row = blockIdx.x, tid = threadIdx.x;
  float4 v = ((const float4*)(in + (long long)row * DD))[tid];
  float s = v.x + v.y + v.z + v.w;
  float q = v.x * v.x + v.y * v.y + v.z * v.z + v.w * v.w;
#pragma unroll
  for (int off = 32; off > 0; off >>= 1) {
    s += __shfl_down(s, off);
    q += __shfl_down(q, off);
  }
  __shared__ float rs[4], rq[4];
  int wv = tid >> 6;
  if ((tid & 63) == 0) { rs[wv] = s; rq[wv] = q; }
  __syncthreads();
  float S = rs[0] + rs[1] + rs[2] + rs[3];
  float Q = rq[0] + rq[1] + rq[2] + rq[3];
  float mean = S * (1.0f / DD);
  float var = Q * (1.0f / DD) - mean * mean;
  float rstd = rsqrtf(var + 1e-5f);
  float4 wv4 = ((const float4*)w)[tid];
  float4 bv4 = ((const float4*)b)[tid];
  float4 r;
  r.x = (v.x - mean) * rstd * wv4.x + bv4.x;
  r.y = (v.y - mean) * rstd * wv4.y + bv4.y;
  r.z = (v.z - mean) * rstd * wv4.z + bv4.z;
  r.w = (v.w - mean) * rstd * wv4.w + bv4.w;
  ((float4*)(out + (long long)row * DD))[tid] = r;
}

// ---------------- fp32 tiled GEMM: C = A(MxK) * B(NxK)^T  [+bias][+relu][+res] ----------------
__global__ __launch_bounds__(256) void gemm_kernel(
    const float* __restrict__ Aall, const float* __restrict__ Ball,
    const float* __restrict__ biasAll, const float* __restrict__ resAll,
    float* __restrict__ Call, int M, int Nn, int Kd, int flags,
    long long sA, long long sB, long long sBias, long long sC) {
  const float* A = Aall + (long long)blockIdx.z * sA;
  const float* B = Ball + (long long)blockIdx.z * sB;
  float* C = Call + (long long)blockIdx.z * sC;

  __shared__ float As[128 * 17];
  __shared__ float Bs[128 * 17];
  int tid = threadIdx.x;
  int tx = tid & 15, ty = tid >> 4;
  int bm = blockIdx.y * 128, bn = blockIdx.x * 128;
  int lrow = tid >> 2;
  int lk = (tid & 3) << 2;

  float acc[8][8];
#pragma unroll
  for (int i = 0; i < 8; i++)
#pragma unroll
    for (int j = 0; j < 8; j++) acc[i][j] = 0.f;

  const float* Arow0 = A + (long long)(bm + lrow) * Kd + lk;
  const float* Arow1 = A + (long long)(bm + lrow + 64) * Kd + lk;
  const float* Brow0 = B + (long long)(bn + lrow) * Kd + lk;
  const float* Brow1 = B + (long long)(bn + lrow + 64) * Kd + lk;

  for (int kb = 0; kb < Kd; kb += 16) {
    float4 a0 = *(const float4*)(Arow0 + kb);
    float4 a1 = *(const float4*)(Arow1 + kb);
    float4 b0 = *(const float4*)(Brow0 + kb);
    float4 b1 = *(const float4*)(Brow1 + kb);
    __syncthreads();
    As[lrow * 17 + lk + 0] = a0.x; As[lrow * 17 + lk + 1] = a0.y;
    As[lrow * 17 + lk + 2] = a0.z; As[lrow * 17 + lk + 3] = a0.w;
    As[(lrow + 64) * 17 + lk + 0] = a1.x; As[(lrow + 64) * 17 + lk + 1] = a1.y;
    As[(lrow + 64) * 17 + lk + 2] = a1.z; As[(lrow + 64) * 17 + lk + 3] = a1.w;
    Bs[lrow * 17 + lk + 0] = b0.x; Bs[lrow * 17 + lk + 1] = b0.y;
    Bs[lrow * 17 + lk + 2] = b0.z; Bs[lrow * 17 + lk + 3] = b0.w;
    Bs[(lrow + 64) * 17 + lk + 0] = b1.x; Bs[(lrow + 64) * 17 + lk + 1] = b1.y;
    Bs[(lrow + 64) * 17 + lk + 2] = b1.z; Bs[(lrow + 64) * 17 + lk + 3] = b1.w;
    __syncthreads();
#pragma unroll
    for (int k = 0; k < 16; k++) {
      float av[8], bv[8];
#pragma unroll
      for (int i = 0; i < 8; i++) av[i] = As[(ty + 16 * i) * 17 + k];
#pragma unroll
      for (int j = 0; j < 8; j++) bv[j] = Bs[(tx + 16 * j) * 17 + k];
#pragma unroll
      for (int i = 0; i < 8; i++)
#pragma unroll
        for (int j = 0; j < 8; j++) acc[i][j] = fmaf(av[i], bv[j], acc[i][j]);
    }
  }

  const float* bias = (flags & 1) ? (biasAll + (long long)blockIdx.z * sBias) : nullptr;
  const float* res = (flags & 4) ? (resAll + (long long)blockIdx.z * sC) : nullptr;
#pragma unroll
  for (int i = 0; i < 8; i++) {
    int row = bm + ty + 16 * i;
#pragma unroll
    for (int j = 0; j < 8; j++) {
      int col = bn + tx + 16 * j;
      float v = acc[i][j];
      if (flags & 1) v += bias[col];
      if (flags & 2) v = fmaxf(v, 0.f);
      if (flags & 4) v += res[(long long)row * Nn + col];
      C[(long long)row * Nn + col] = v;
    }
  }
}

// ---------------- RoPE in place on q,k inside qkv buffer ----------------
__global__ __launch_bounds__(256) void rope_kernel(float* __restrict__ qkv,
                                                   const float* __restrict__ st,
                                                   const float* __restrict__ ct) {
  int t = blockIdx.x, tid = threadIdx.x;
#pragma unroll
  for (int p = tid; p < HH * HALF; p += 256) {
    int h = p >> 5, i = p & 31;
    float s = st[t * HALF + i], c = ct[t * HALF + i];
    float* q = qkv + (long long)t * (3 * DD) + h * HSS;
    float q1 = q[i], q2 = q[i + HALF];
    q[i] = q1 * c - q2 * s;
    q[i + HALF] = q2 * c + q1 * s;
    float* k = q + DD;
    float k1 = k[i], k2 = k[i + HALF];
    k[i] = k1 * c - k2 * s;
    k[i + HALF] = k2 * c + k1 * s;
  }
}

// ---------------- flash attention v2: key-split across 4 waves ----------------
// Grid: 512 blocks x 256 threads. Block = (head, 64 q-rows); wave w handles
// 64-key tiles w, w+4, ... with private online-softmax state; states merged
// at the end via LDS. Output written in [H, T, HS] (head-major) layout to
// reproduce the reference's av.transpose(0,2,1,3).reshape(B,T,D).
// blockIdx->(head,qc) mapping pairs heavy (qc>=16) and light blocks per CU.
__global__ __launch_bounds__(256) void attn_kernel(const float* __restrict__ qkv,
                                                   float* __restrict__ attn) {
  int bid = blockIdx.x;
  int head = bid & 15;
  int qc = (bid < 256) ? (31 - (bid >> 4)) : ((bid - 256) >> 4);
  int tid = threadIdx.x;
  int w = tid >> 6;   // wave 0..3 = key split
  int r = tid & 63;   // q row within chunk
  int qrow = qc * 64 + r;
  int nkt = qc + 1;   // 64-key tiles in causal range

  // per-wave K/V staging: [wave][K/V][16 keys][16 float4]; 32 KB.
  // Aliased after the main loop as the merge buffer Osc[4][64][5] float4.
  __shared__ float4 KVbuf[4][2][16][16];
  __shared__ float Ms[4][64];
  __shared__ float Ls[4][64];

  float4 q[16], o[16];
  const float4* qp = (const float4*)(qkv + (long long)qrow * (3 * DD) + head * HSS);
#pragma unroll
  for (int d = 0; d < 16; d++) { q[d] = qp[d]; o[d] = make_float4(0.f, 0.f, 0.f, 0.f); }
  float m = -INFINITY, l = 0.f;

  for (int kt = w; kt < nkt; kt += 4) {
    bool diag = (kt == qc);
#pragma unroll 1
    for (int s = 0; s < 4; s++) {
      int kbase = kt * 64 + s * 16;
      // stage 16 K rows + 16 V rows (wave-private; no block barrier needed)
#pragma unroll
      for (int it = 0; it < 4; it++) {
        int fid = r + it * 64;
        int krow = fid >> 4, d4 = fid & 15;
        const float* bK = qkv + (long long)(kbase + krow) * (3 * DD) + DD + head * HSS + d4 * 4;
        KVbuf[w][0][krow][d4] = *(const float4*)bK;
        KVbuf[w][1][krow][d4] = *(const float4*)(bK + DD);
      }
      float sbuf[16];
#pragma unroll
      for (int jj = 0; jj < 16; jj++) {
        const float4* kr = KVbuf[w][0][jj];
        float sv = 0.f;
#pragma unroll
        for (int d = 0; d < 16; d++) {
          float4 kv = kr[d];
          sv = fmaf(q[d].x, kv.x, sv); sv = fmaf(q[d].y, kv.y, sv);
          sv = fmaf(q[d].z, kv.z, sv); sv = fmaf(q[d].w, kv.w, sv);
        }
        sv *= 0.125f;  // 1/sqrt(64)
        // NOTE: s=0 of a wave's first tile always has >=1 unmasked key per
        // row, so m is finite before any fully-masked subtile is reached.
        if (diag && (kbase + jj > qrow)) sv = -1e30f;
        sbuf[jj] = sv;
      }
      float gm = m;
#pragma unroll
      for (int jj = 0; jj < 16; jj++) gm = fmaxf(gm, sbuf[jj]);
      float scale = __expf(m - gm);
      m = gm;
      l *= scale;
#pragma unroll
      for (int d = 0; d < 16; d++) {
        o[d].x *= scale; o[d].y *= scale; o[d].z *= scale; o[d].w *= scale;
      }
#pragma unroll
      for (int jj = 0; jj < 16; jj++) {
        float p = __expf(sbuf[jj] - m);
        l += p;
        const float4* vr = KVbuf[w][1][jj];
#pragma unroll
        for (int d = 0; d < 16; d++) {
          float4 vv = vr[d];
          o[d].x = fmaf(p, vv.x, o[d].x); o[d].y = fmaf(p, vv.y, o[d].y);
          o[d].z = fmaf(p, vv.z, o[d].z); o[d].w = fmaf(p, vv.w, o[d].w);
        }
      }
    }
  }

  // ---- cross-wave merge, chunked over 4 x 16 floats (reuses KVbuf LDS) ----
  typedef float4 OscRow[64][5];
  OscRow* Osc = reinterpret_cast<OscRow*>(&KVbuf[0][0][0][0]);  // [4][64][5], 20 KB
  int rr = tid & 63, ii = tid >> 6;
  long long obase = (long long)head * TT * HSS + (long long)(qc * 64 + rr) * HSS;
#pragma unroll 1
  for (int c = 0; c < 4; c++) {
    __syncthreads();  // first iter: all waves done with KVbuf; later: buffer reuse
    Osc[w][r][0] = o[c * 4 + 0];
    Osc[w][r][1] = o[c * 4 + 1];
    Osc[w][r][2] = o[c * 4 + 2];
    Osc[w][r][3] = o[c * 4 + 3];
    if (c == 0) { Ms[w][r] = m; Ls[w][r] = l; }
    __syncthreads();
    float m0 = Ms[0][rr], m1 = Ms[1][rr], m2 = Ms[2][rr], m3 = Ms[3][rr];
    float M = fmaxf(fmaxf(m0, m1), fmaxf(m2, m3));
    float s0 = __expf(m0 - M), s1 = __expf(m1 - M);
    float s2 = __expf(m2 - M), s3 = __expf(m3 - M);
    float L = s0 * Ls[0][rr] + s1 * Ls[1][rr] + s2 * Ls[2][rr] + s3 * Ls[3][rr];
    float rl = 1.f / L;
    float4 a0 = Osc[0][rr][ii], a1 = Osc[1][rr][ii];
    float4 a2 = Osc[2][rr][ii], a3 = Osc[3][rr][ii];
    float4 res;
    res.x = (s0 * a0.x + s1 * a1.x + s2 * a2.x + s3 * a3.x) * rl;
    res.y = (s0 * a0.y + s1 * a1.y + s2 * a2.y + s3 * a3.y) * rl;
    res.z = (s0 * a0.z + s1 * a1.z + s2 * a2.z + s3 * a3.z) * rl;
    res.w = (s0 * a0.w + s1 * a1.w + s2 * a2.w + s3 * a3.w) * rl;
    *(float4*)(attn + obase + c * 16 + ii * 4) = res;
  }
}

// ---------------- router: logits, noisy top-2, gates (double accumulation) ----------------
__global__ __launch_bounds__(64) void router_kernel(
    const float* __restrict__ y, const float* __restrict__ rw, const float* __restrict__ rb,
    const float* __restrict__ nw, const float* __restrict__ nb, const float* __restrict__ noise,
    int* __restrict__ slot_e, float* __restrict__ slot_g) {
  int n = blockIdx.x;
  int lane = threadIdx.x;
  double accr[EE], accn[EE];
#pragma unroll
  for (int e = 0; e < EE; e++) { accr[e] = 0.0; accn[e] = 0.0; }
  for (int j = 0; j < 16; j++) {
    float xv = y[(long long)n * DD + j * 64 + lane];
#pragma unroll
    for (int e = 0; e < EE; e++) {
      accr[e] += (double)xv * (double)rw[e * DD + j * 64 + lane];
      accn[e] += (double)xv * (double)nw[e * DD + j * 64 + lane];
    }
  }
#pragma unroll
  for (int e = 0; e < EE; e++) {
    for (int off = 32; off > 0; off >>= 1) {
      accr[e] += __shfl_down(accr[e], off);
      accn[e] += __shfl_down(accn[e], off);
    }
  }
  if (lane == 0) {
    float noisy[EE];
#pragma unroll
    for (int e = 0; e < EE; e++) {
      float lg = (float)accr[e] + rb[e];
      float nl = (float)accn[e] + nb[e];
      float sp = (nl > 0.f) ? (nl + log1pf(expf(-nl))) : log1pf(expf(nl));
      noisy[e] = lg + noise[n * EE + e] * sp;
    }
    int i0 = 0;
#pragma unroll
    for (int e = 1; e < EE; e++) if (noisy[e] > noisy[i0]) i0 = e;
    int i1 = -1;
#pragma unroll
    for (int e = 0; e < EE; e++) {
      if (e == i0) continue;
      if (i1 < 0 || noisy[e] > noisy[i1]) i1 = e;
    }
    float v0 = noisy[i0], v1 = noisy[i1];
    float e1 = __expf(v1 - v0);
    float inv = 1.f / (1.f + e1);
    slot_e[2 * n] = i0; slot_e[2 * n + 1] = i1;
    slot_g[2 * n] = inv; slot_g[2 * n + 1] = e1 * inv;
  }
}

// ---------------- deterministic rank scan (flattened N*K order) ----------------
__global__ __launch_bounds__(256) void scan_kernel(const int* __restrict__ slot_e,
                                                   int* __restrict__ slot_pos) {
  __shared__ int cnt[256 * EE];
  int tid = threadIdx.x;
  int base = tid * 16;  // 4096 / 256
  int c[EE];
#pragma unroll
  for (int e = 0; e < EE; e++) c[e] = 0;
  int loc[16];
  for (int i = 0; i < 16; i++) {
    int e = slot_e[base + i];
    loc[i] = e;
    c[e]++;
  }
#pragma unroll
  for (int e = 0; e < EE; e++) cnt[tid * EE + e] = c[e];
  __syncthreads();
  if (tid < EE) {
    int run = 0;
    for (int t2 = 0; t2 < 256; t2++) {
      int v = cnt[t2 * EE + tid];
      cnt[t2 * EE + tid] = run;
      run += v;
    }
  }
  __syncthreads();
  int run[EE];
#pragma unroll
  for (int e = 0; e < EE; e++) run[e] = cnt[tid * EE + e];
  for (int i = 0; i < 16; i++) {
    int e = loc[i];
    int r = run[e]++;
    slot_pos[base + i] = (r < CAPP) ? (e * CAPP + r) : -1;
  }
}

// ---------------- dispatch: disp[pos] = y[token] ----------------
__global__ __launch_bounds__(256) void dispatch_kernel(const float* __restrict__ y,
                                                       const int* __restrict__ slot_pos,
                                                       float* __restrict__ disp) {
  int i = blockIdx.x;
  int pos = slot_pos[i];
  if (pos < 0) return;
  int tok = i >> 1;
  ((float4*)(disp + (long long)pos * DD))[threadIdx.x] =
      ((const float4*)(y + (long long)tok * DD))[threadIdx.x];
}

// ---------------- combine: x += sum_k gate_k * eo[pos_k] ----------------
__global__ __launch_bounds__(256) void combine_kernel(float* __restrict__ x,
                                                      const float* __restrict__ eo,
                                                      const int* __restrict__ slot_pos,
                                                      const float* __restrict__ slot_g) {
  int n = blockIdx.x, tid = threadIdx.x;
  int p0 = slot_pos[2 * n], p1 = slot_pos[2 * n + 1];
  float g0 = slot_g[2 * n], g1 = slot_g[2 * n + 1];
  float4 v = ((float4*)(x + (long long)n * DD))[tid];
  if (p0 >= 0) {
    float4 e0 = ((const float4*)(eo + (long long)p0 * DD))[tid];
    v.x = fmaf(g0, e0.x, v.x); v.y = fmaf(g0, e0.y, v.y);
    v.z = fmaf(g0, e0.z, v.z); v.w = fmaf(g0, e0.w, v.w);
  }
  if (p1 >= 0) {
    float4 e1 = ((const float4*)(eo + (long long)p1 * DD))[tid];
    v.x = fmaf(g1, e1.x, v.x); v.y = fmaf(g1, e1.y, v.y);
    v.z = fmaf(g1, e1.z, v.z); v.w = fmaf(g1, e1.w, v.w);
  }
  ((float4*)(x + (long long)n * DD))[tid] = v;
}

extern "C" void kernel_launch(void* const* d_in, const int* in_sizes, int n_in,
                              void* d_out, int out_size, void* d_ws, size_t ws_size,
                              hipStream_t stream) {
  const int* input_ids = (const int*)d_in[0];
  const float* noise = (const float*)d_in[1];
  const float* tok_emb = (const float*)d_in[2];
  const float* pos_emb = (const float*)d_in[3];
  const float* ln1_w = (const float*)d_in[4];
  const float* ln1_b = (const float*)d_in[5];
  const float* ln2_w = (const float*)d_in[6];
  const float* ln2_b = (const float*)d_in[7];
  const float* qkv_w = (const float*)d_in[8];
  const float* out_w = (const float*)d_in[9];
  const float* router_w = (const float*)d_in[10];
  const float* router_b = (const float*)d_in[11];
  const float* noise_w = (const float*)d_in[12];
  const float* noise_b = (const float*)d_in[13];
  const float* e_w1 = (const float*)d_in[14];
  const float* e_b1 = (const float*)d_in[15];
  const float* e_w2 = (const float*)d_in[16];
  const float* e_b2 = (const float*)d_in[17];
  const float* lnf_w = (const float*)d_in[18];
  const float* lnf_b = (const float*)d_in[19];
  float* out = (float*)d_out;

  float* ws = (float*)d_ws;
  float* x = ws;                                    // N*D
  float* y = x + (size_t)NN * DD;                   // N*D
  float* qkv = y + (size_t)NN * DD;                 // N*3D
  float* attn = qkv + (size_t)NN * 3 * DD;          // N*D  ([H,T,HS] layout)
  float* disp = attn + (size_t)NN * DD;             // E*CAP*D
  float* hbuf = disp + (size_t)EE * CAPP * DD;      // E*CAP*4D
  float* eo = hbuf + (size_t)EE * CAPP * DFF;       // E*CAP*D
  float* sintab = eo + (size_t)EE * CAPP * DD;      // T*HALF
  float* costab = sintab + (size_t)TT * HALF;       // T*HALF
  int* slot_e = (int*)(costab + (size_t)TT * HALF); // NK
  int* slot_pos = slot_e + NK;                      // NK
  float* slot_g = (float*)(slot_pos + NK);          // NK

  embed_kernel<<<TT, 256, 0, stream>>>(input_ids, tok_emb, pos_emb, x);
  sincos_kernel<<<(TT * HALF) / 256, 256, 0, stream>>>(sintab, costab);

  for (int l = 0; l < LL; l++) {
    ln_kernel<<<NN, 256, 0, stream>>>(x, y, ln1_w + l * DD, ln1_b + l * DD);
    gemm_kernel<<<dim3(3 * DD / 128, NN / 128, 1), 256, 0, stream>>>(
        y, qkv_w + (size_t)l * 3 * DD * DD, nullptr, nullptr, qkv,
        NN, 3 * DD, DD, 0, 0, 0, 0, 0);
    rope_kernel<<<TT, 256, 0, stream>>>(qkv, sintab, costab);
    attn_kernel<<<512, 256, 0, stream>>>(qkv, attn);
    gemm_kernel<<<dim3(DD / 128, NN / 128, 1), 256, 0, stream>>>(
        attn, out_w + (size_t)l * DD * DD, nullptr, x, x,
        NN, DD, DD, 4, 0, 0, 0, 0);
    ln_kernel<<<NN, 256, 0, stream>>>(x, y, ln2_w + l * DD, ln2_b + l * DD);
    router_kernel<<<NN, 64, 0, stream>>>(
        y, router_w + (size_t)l * EE * DD, router_b + l * EE,
        noise_w + (size_t)l * EE * DD, noise_b + l * EE,
        noise + (size_t)l * NN * EE, slot_e, slot_g);
    scan_kernel<<<1, 256, 0, stream>>>(slot_e, slot_pos);
    dispatch_kernel<<<NK, 256, 0, stream>>>(y, slot_pos, disp);
    gemm_kernel<<<dim3(DFF / 128, CAPP / 128, EE), 256, 0, stream>>>(
        disp, e_w1 + (size_t)l * EE * DFF * DD, e_b1 + (size_t)l * EE * DFF, nullptr, hbuf,
        CAPP, DFF, DD, 3,
        (long long)CAPP * DD, (long long)DFF * DD, DFF, (long long)CAPP * DFF);
    gemm_kernel<<<dim3(DD / 128, CAPP / 128, EE), 256, 0, stream>>>(
        hbuf, e_w2 + (size_t)l * EE * DD * DFF, e_b2 + (size_t)l * EE * DD, nullptr, eo,
        CAPP, DD, DFF, 1,
        (long long)CAPP * DFF, (long long)DD * DFF, DD, (long long)CAPP * DD);
    combine_kernel<<<NN, 256, 0, stream>>>(x, eo, slot_pos, slot_g);
  }
  ln_kernel<<<NN, 256, 0, stream>>>(x, out, lnf_w, lnf_b);
  (void)in_sizes; (void)n_in; (void)out_size; (void)ws_size;
}

// Round 4
// 2875.869 us; speedup vs baseline: 3.0354x; 3.0354x over previous
//
#include <hip/hip_runtime.h>
#include <math.h>

#define TT   2048
#define DD   1024
#define HH   16
#define HSS  64
#define EE   8
#define KTOP 2
#define LL   2
#define CAPP 512
#define NN   2048
#define DFF  4096
#define NK   (NN*KTOP)
#define HALF 32

typedef __attribute__((ext_vector_type(8))) short bf16x8;
typedef __attribute__((ext_vector_type(4))) float f32x4;

// split fp32 v into 3 bf16 planes (RNE bit-math; v = s0 + s1 + s2 to ~2^-27 rel)
__device__ __forceinline__ void split3(float v, short& s0, short& s1, short& s2) {
  union { float f; unsigned u; } a, b0, c, b1, d;
  a.f = v;
  unsigned t0 = (a.u + 0x7fffu + ((a.u >> 16) & 1u)) & 0xffff0000u;
  b0.u = t0;
  float r1 = v - b0.f;
  c.f = r1;
  unsigned t1 = (c.u + 0x7fffu + ((c.u >> 16) & 1u)) & 0xffff0000u;
  b1.u = t1;
  float r2 = r1 - b1.f;
  d.f = r2;
  unsigned t2 = d.u + 0x7fffu + ((d.u >> 16) & 1u);
  s0 = (short)(t0 >> 16); s1 = (short)(t1 >> 16); s2 = (short)(t2 >> 16);
}

// ---------------- embedding ----------------
__global__ __launch_bounds__(256) void embed_kernel(const int* __restrict__ ids,
                                                    const float* __restrict__ tok,
                                                    const float* __restrict__ pos,
                                                    float* __restrict__ x) {
  int t = blockIdx.x, tid = threadIdx.x;
  int id = ids[t];
  float4 a = ((const float4*)(tok + (long long)id * DD))[tid];
  float4 b = ((const float4*)(pos + (long long)t * DD))[tid];
  float4 r;
  r.x = a.x + b.x; r.y = a.y + b.y; r.z = a.z + b.z; r.w = a.w + b.w;
  ((float4*)(x + (long long)t * DD))[tid] = r;
}

// ---------------- RoPE sin/cos table ----------------
__global__ __launch_bounds__(256) void sincos_kernel(float* __restrict__ st, float* __restrict__ ct) {
  int idx = blockIdx.x * 256 + threadIdx.x;
  int t = idx >> 5, i = idx & 31;
  double div = exp(-(double)(2 * i) * (9.210340371976184 / 64.0));
  double a = (double)t * div;
  st[idx] = (float)sin(a);
  ct[idx] = (float)cos(a);
}

// ---------------- fp32 -> 3 bf16 plane conversion (8 elems/thread) ----------------
__global__ __launch_bounds__(256) void convert_kernel(const float* __restrict__ in,
                                                      short* __restrict__ out, long long n) {
  long long i = ((long long)blockIdx.x * 256 + threadIdx.x) * 8;
  float4 v0 = *(const float4*)(in + i);
  float4 v1 = *(const float4*)(in + i + 4);
  float vv[8] = {v0.x, v0.y, v0.z, v0.w, v1.x, v1.y, v1.z, v1.w};
  short s0[8], s1[8], s2[8];
#pragma unroll
  for (int j = 0; j < 8; j++) split3(vv[j], s0[j], s1[j], s2[j]);
  *(short4*)(out + i)         = make_short4(s0[0], s0[1], s0[2], s0[3]);
  *(short4*)(out + i + 4)     = make_short4(s0[4], s0[5], s0[6], s0[7]);
  *(short4*)(out + n + i)     = make_short4(s1[0], s1[1], s1[2], s1[3]);
  *(short4*)(out + n + i + 4) = make_short4(s1[4], s1[5], s1[6], s1[7]);
  *(short4*)(out + 2*n + i)   = make_short4(s2[0], s2[1], s2[2], s2[3]);
  *(short4*)(out + 2*n + i+4) = make_short4(s2[4], s2[5], s2[6], s2[7]);
}

// ---------------- layernorm (+ optional bf16x3 plane output) ----------------
__global__ __launch_bounds__(256) void ln_kernel(const float* __restrict__ in, float* __restrict__ out,
                                                 short* __restrict__ yp,
                                                 const float* __restrict__ w, const float* __restrict__ b) {
  int row = blockIdx.x, tid = threadIdx.x;
  float4 v = ((const float4*)(in + (long long)row * DD))[tid];
  float s = v.x + v.y + v.z + v.w;
  float q = v.x * v.x + v.y * v.y + v.z * v.z + v.w * v.w;
#pragma unroll
  for (int off = 32; off > 0; off >>= 1) {
    s += __shfl_down(s, off);
    q += __shfl_down(q, off);
  }
  __shared__ float rs[4], rq[4];
  int wv = tid >> 6;
  if ((tid & 63) == 0) { rs[wv] = s; rq[wv] = q; }
  __syncthreads();
  float S = rs[0] + rs[1] + rs[2] + rs[3];
  float Q = rq[0] + rq[1] + rq[2] + rq[3];
  float mean = S * (1.0f / DD);
  float var = Q * (1.0f / DD) - mean * mean;
  float rstd = rsqrtf(var + 1e-5f);
  float4 wv4 = ((const float4*)w)[tid];
  float4 bv4 = ((const float4*)b)[tid];
  float4 r;
  r.x = (v.x - mean) * rstd * wv4.x + bv4.x;
  r.y = (v.y - mean) * rstd * wv4.y + bv4.y;
  r.z = (v.z - mean) * rstd * wv4.z + bv4.z;
  r.w = (v.w - mean) * rstd * wv4.w + bv4.w;
  ((float4*)(out + (long long)row * DD))[tid] = r;
  if (yp) {
    float rr[4] = {r.x, r.y, r.z, r.w};
    short a0[4], a1[4], a2[4];
#pragma unroll
    for (int j = 0; j < 4; j++) split3(rr[j], a0[j], a1[j], a2[j]);
    size_t off = (size_t)row * DD + tid * 4;
    *(short4*)(yp + off)                    = make_short4(a0[0], a0[1], a0[2], a0[3]);
    *(short4*)(yp + (size_t)NN*DD + off)    = make_short4(a1[0], a1[1], a1[2], a1[3]);
    *(short4*)(yp + (size_t)2*NN*DD + off)  = make_short4(a2[0], a2[1], a2[2], a2[3]);
  }
}

// ---------------- fp32 tiled GEMM (fallback path) ----------------
__global__ __launch_bounds__(256) void gemm_kernel(
    const float* __restrict__ Aall, const float* __restrict__ Ball,
    const float* __restrict__ biasAll, const float* __restrict__ resAll,
    float* __restrict__ Call, int M, int Nn, int Kd, int flags,
    long long sA, long long sB, long long sBias, long long sC) {
  const float* A = Aall + (long long)blockIdx.z * sA;
  const float* B = Ball + (long long)blockIdx.z * sB;
  float* C = Call + (long long)blockIdx.z * sC;
  __shared__ float As[128 * 17];
  __shared__ float Bs[128 * 17];
  int tid = threadIdx.x;
  int tx = tid & 15, ty = tid >> 4;
  int bm = blockIdx.y * 128, bn = blockIdx.x * 128;
  int lrow = tid >> 2;
  int lk = (tid & 3) << 2;
  float acc[8][8];
#pragma unroll
  for (int i = 0; i < 8; i++)
#pragma unroll
    for (int j = 0; j < 8; j++) acc[i][j] = 0.f;
  const float* Arow0 = A + (long long)(bm + lrow) * Kd + lk;
  const float* Arow1 = A + (long long)(bm + lrow + 64) * Kd + lk;
  const float* Brow0 = B + (long long)(bn + lrow) * Kd + lk;
  const float* Brow1 = B + (long long)(bn + lrow + 64) * Kd + lk;
  for (int kb = 0; kb < Kd; kb += 16) {
    float4 a0 = *(const float4*)(Arow0 + kb);
    float4 a1 = *(const float4*)(Arow1 + kb);
    float4 b0 = *(const float4*)(Brow0 + kb);
    float4 b1 = *(const float4*)(Brow1 + kb);
    __syncthreads();
    As[lrow * 17 + lk + 0] = a0.x; As[lrow * 17 + lk + 1] = a0.y;
    As[lrow * 17 + lk + 2] = a0.z; As[lrow * 17 + lk + 3] = a0.w;
    As[(lrow + 64) * 17 + lk + 0] = a1.x; As[(lrow + 64) * 17 + lk + 1] = a1.y;
    As[(lrow + 64) * 17 + lk + 2] = a1.z; As[(lrow + 64) * 17 + lk + 3] = a1.w;
    Bs[lrow * 17 + lk + 0] = b0.x; Bs[lrow * 17 + lk + 1] = b0.y;
    Bs[lrow * 17 + lk + 2] = b0.z; Bs[lrow * 17 + lk + 3] = b0.w;
    Bs[(lrow + 64) * 17 + lk + 0] = b1.x; Bs[(lrow + 64) * 17 + lk + 1] = b1.y;
    Bs[(lrow + 64) * 17 + lk + 2] = b1.z; Bs[(lrow + 64) * 17 + lk + 3] = b1.w;
    __syncthreads();
#pragma unroll
    for (int k = 0; k < 16; k++) {
      float av[8], bv[8];
#pragma unroll
      for (int i = 0; i < 8; i++) av[i] = As[(ty + 16 * i) * 17 + k];
#pragma unroll
      for (int j = 0; j < 8; j++) bv[j] = Bs[(tx + 16 * j) * 17 + k];
#pragma unroll
      for (int i = 0; i < 8; i++)
#pragma unroll
        for (int j = 0; j < 8; j++) acc[i][j] = fmaf(av[i], bv[j], acc[i][j]);
    }
  }
  const float* bias = (flags & 1) ? (biasAll + (long long)blockIdx.z * sBias) : nullptr;
  const float* res = (flags & 4) ? (resAll + (long long)blockIdx.z * sC) : nullptr;
#pragma unroll
  for (int i = 0; i < 8; i++) {
    int row = bm + ty + 16 * i;
#pragma unroll
    for (int j = 0; j < 8; j++) {
      int col = bn + tx + 16 * j;
      float v = acc[i][j];
      if (flags & 1) v += bias[col];
      if (flags & 2) v = fmaxf(v, 0.f);
      if (flags & 4) v += res[(long long)row * Nn + col];
      C[(long long)row * Nn + col] = v;
    }
  }
}

// ---------------- bf16x3 emulated-fp32 MFMA GEMM ----------------
// C = A(MxK) * B(NxK)^T from pre-split bf16 planes (Ap/Bp: [3][batch][rows][K]).
// flags: 1=bias, 2=relu, 4=residual(fp32 C only), 8=fast(3 products), 16=C as bf16x3 planes.
// 128x128 tile, 256 thr = 4 waves (2x2 of 64x64), 16x16x32 bf16 MFMA.
__global__ __launch_bounds__(256, 1) void gemm_mfma(
    const short* __restrict__ Ap, const short* __restrict__ Bp,
    const float* __restrict__ biasAll, const float* __restrict__ resAll,
    void* __restrict__ Call, int M, int Nn, int Kd, int flags,
    long long sA, long long sB, long long sBias, long long sC,
    long long PA, long long PB, long long PC) {
  const bool fast = (flags & 8);
  const int np = fast ? 2 : 3;
  __shared__ short As[3][128][40];  // +8 pad per row: conflict-free b128 frag reads
  __shared__ short Bs[3][128][40];
  int tid = threadIdx.x;
  int bm = blockIdx.y * 128, bn = blockIdx.x * 128;
  long long zA = (long long)blockIdx.z * sA;
  long long zB = (long long)blockIdx.z * sB;
  int srow = tid >> 1, scol = (tid & 1) * 16;
  const short* Abase = Ap + zA + (long long)(bm + srow) * Kd + scol;
  const short* Bbase = Bp + zB + (long long)(bn + srow) * Kd + scol;

  int wid = tid >> 6, lane = tid & 63;
  int wm = (wid & 1) * 64, wn = (wid >> 1) * 64;
  int tr = lane & 15, quad = lane >> 4;

  f32x4 acc[4][4];
#pragma unroll
  for (int i = 0; i < 4; i++)
#pragma unroll
    for (int j = 0; j < 4; j++) acc[i][j] = (f32x4){0.f, 0.f, 0.f, 0.f};

  for (int kb = 0; kb < Kd; kb += 32) {
    __syncthreads();
#pragma unroll
    for (int p = 0; p < 3; p++) {
      if (p < np) {
        bf16x8 a0 = *(const bf16x8*)(Abase + p * PA + kb);
        bf16x8 a1 = *(const bf16x8*)(Abase + p * PA + kb + 8);
        *(bf16x8*)&As[p][srow][scol] = a0;
        *(bf16x8*)&As[p][srow][scol + 8] = a1;
        bf16x8 b0 = *(const bf16x8*)(Bbase + p * PB + kb);
        bf16x8 b1 = *(const bf16x8*)(Bbase + p * PB + kb + 8);
        *(bf16x8*)&Bs[p][srow][scol] = b0;
        *(bf16x8*)&Bs[p][srow][scol + 8] = b1;
      }
    }
    __syncthreads();
    bf16x8 af[4][3];
#pragma unroll
    for (int mi = 0; mi < 4; mi++) {
      int ar = wm + mi * 16 + tr;
      af[mi][0] = *(const bf16x8*)&As[0][ar][quad * 8];
      af[mi][1] = *(const bf16x8*)&As[1][ar][quad * 8];
      af[mi][2] = fast ? af[mi][0] : *(const bf16x8*)&As[2][ar][quad * 8];
    }
#pragma unroll
    for (int nj = 0; nj < 4; nj++) {
      int br = wn + nj * 16 + tr;
      bf16x8 b0 = *(const bf16x8*)&Bs[0][br][quad * 8];
      bf16x8 b1 = *(const bf16x8*)&Bs[1][br][quad * 8];
      bf16x8 b2 = fast ? b0 : *(const bf16x8*)&Bs[2][br][quad * 8];
#pragma unroll
      for (int mi = 0; mi < 4; mi++) {
        f32x4 c = acc[mi][nj];
        c = __builtin_amdgcn_mfma_f32_16x16x32_bf16(af[mi][1], b0, c, 0, 0, 0); // a1b0
        c = __builtin_amdgcn_mfma_f32_16x16x32_bf16(af[mi][0], b1, c, 0, 0, 0); // a0b1
        if (!fast) {
          c = __builtin_amdgcn_mfma_f32_16x16x32_bf16(af[mi][2], b0, c, 0, 0, 0); // a2b0
          c = __builtin_amdgcn_mfma_f32_16x16x32_bf16(af[mi][1], b1, c, 0, 0, 0); // a1b1
          c = __builtin_amdgcn_mfma_f32_16x16x32_bf16(af[mi][0], b2, c, 0, 0, 0); // a0b2
        }
        c = __builtin_amdgcn_mfma_f32_16x16x32_bf16(af[mi][0], b0, c, 0, 0, 0);   // a0b0
        acc[mi][nj] = c;
      }
    }
  }

  long long z = blockIdx.z;
  const float* bias = (flags & 1) ? (biasAll + z * sBias) : nullptr;
  if (flags & 16) {
    short* Cs = (short*)Call;
#pragma unroll
    for (int mi = 0; mi < 4; mi++)
#pragma unroll
      for (int nj = 0; nj < 4; nj++) {
        int col = bn + wn + nj * 16 + tr;
#pragma unroll
        for (int rg = 0; rg < 4; rg++) {
          int row = bm + wm + mi * 16 + quad * 4 + rg;
          float v = acc[mi][nj][rg];
          if (flags & 1) v += bias[col];
          if (flags & 2) v = fmaxf(v, 0.f);
          short s0, s1, s2;
          split3(v, s0, s1, s2);
          long long off = z * sC + (long long)row * Nn + col;
          Cs[off] = s0; Cs[PC + off] = s1; Cs[2 * PC + off] = s2;
        }
      }
  } else {
    float* C = (float*)Call;
    const float* res = (flags & 4) ? (resAll + z * sC) : nullptr;
#pragma unroll
    for (int mi = 0; mi < 4; mi++)
#pragma unroll
      for (int nj = 0; nj < 4; nj++) {
        int col = bn + wn + nj * 16 + tr;
#pragma unroll
        for (int rg = 0; rg < 4; rg++) {
          int row = bm + wm + mi * 16 + quad * 4 + rg;
          float v = acc[mi][nj][rg];
          if (flags & 1) v += bias[col];
          if (flags & 2) v = fmaxf(v, 0.f);
          if (flags & 4) v += res[(long long)row * Nn + col];
          C[z * sC + (long long)row * Nn + col] = v;
        }
      }
  }
}

// ---------------- RoPE in place ----------------
__global__ __launch_bounds__(256) void rope_kernel(float* __restrict__ qkv,
                                                   const float* __restrict__ st,
                                                   const float* __restrict__ ct) {
  int t = blockIdx.x, tid = threadIdx.x;
#pragma unroll
  for (int p = tid; p < HH * HALF; p += 256) {
    int h = p >> 5, i = p & 31;
    float s = st[t * HALF + i], c = ct[t * HALF + i];
    float* q = qkv + (long long)t * (3 * DD) + h * HSS;
    float q1 = q[i], q2 = q[i + HALF];
    q[i] = q1 * c - q2 * s;
    q[i + HALF] = q2 * c + q1 * s;
    float* k = q + DD;
    float k1 = k[i], k2 = k[i + HALF];
    k[i] = k1 * c - k2 * s;
    k[i + HALF] = k2 * c + k1 * s;
  }
}

// ---------------- flash attention: key-split across 4 waves ----------------
// (256,1): allow high VGPR; merge loop fully unrolled (NO dynamic reg indexing).
__global__ __launch_bounds__(256, 1) void attn_kernel(const float* __restrict__ qkv,
                                                      float* __restrict__ attn,
                                                      short* __restrict__ ap) {
  int bid = blockIdx.x;
  int head = bid & 15;
  int qc = (bid < 256) ? (31 - (bid >> 4)) : ((bid - 256) >> 4);
  int tid = threadIdx.x;
  int w = tid >> 6;
  int r = tid & 63;
  int qrow = qc * 64 + r;
  int nkt = qc + 1;

  __shared__ float4 KVbuf[4][2][16][16];
  __shared__ float Ms[4][64];
  __shared__ float Ls[4][64];

  float4 q[16], o[16];
  const float4* qp = (const float4*)(qkv + (long long)qrow * (3 * DD) + head * HSS);
#pragma unroll
  for (int d = 0; d < 16; d++) { q[d] = qp[d]; o[d] = make_float4(0.f, 0.f, 0.f, 0.f); }
  float m = -INFINITY, l = 0.f;

  for (int kt = w; kt < nkt; kt += 4) {
    bool diag = (kt == qc);
#pragma unroll 1
    for (int s = 0; s < 4; s++) {
      int kbase = kt * 64 + s * 16;
#pragma unroll
      for (int it = 0; it < 4; it++) {
        int fid = r + it * 64;
        int krow = fid >> 4, d4 = fid & 15;
        const float* bK = qkv + (long long)(kbase + krow) * (3 * DD) + DD + head * HSS + d4 * 4;
        KVbuf[w][0][krow][d4] = *(const float4*)bK;
        KVbuf[w][1][krow][d4] = *(const float4*)(bK + DD);
      }
      float sbuf[16];
#pragma unroll
      for (int jj = 0; jj < 16; jj++) {
        const float4* kr = KVbuf[w][0][jj];
        float sv = 0.f;
#pragma unroll
        for (int d = 0; d < 16; d++) {
          float4 kv = kr[d];
          sv = fmaf(q[d].x, kv.x, sv); sv = fmaf(q[d].y, kv.y, sv);
          sv = fmaf(q[d].z, kv.z, sv); sv = fmaf(q[d].w, kv.w, sv);
        }
        sv *= 0.125f;
        if (diag && (kbase + jj > qrow)) sv = -1e30f;
        sbuf[jj] = sv;
      }
      float gm = m;
#pragma unroll
      for (int jj = 0; jj < 16; jj++) gm = fmaxf(gm, sbuf[jj]);
      float scale = __expf(m - gm);
      m = gm;
      l *= scale;
#pragma unroll
      for (int d = 0; d < 16; d++) {
        o[d].x *= scale; o[d].y *= scale; o[d].z *= scale; o[d].w *= scale;
      }
#pragma unroll
      for (int jj = 0; jj < 16; jj++) {
        float p = __expf(sbuf[jj] - m);
        l += p;
        const float4* vr = KVbuf[w][1][jj];
#pragma unroll
        for (int d = 0; d < 16; d++) {
          float4 vv = vr[d];
          o[d].x = fmaf(p, vv.x, o[d].x); o[d].y = fmaf(p, vv.y, o[d].y);
          o[d].z = fmaf(p, vv.z, o[d].z); o[d].w = fmaf(p, vv.w, o[d].w);
        }
      }
    }
  }

  // cross-wave merge (FULLY unrolled: constant indices into o[])
  typedef float4 OscRow[64][5];
  OscRow* Osc = reinterpret_cast<OscRow*>(&KVbuf[0][0][0][0]);
  int rr = tid & 63, ii = tid >> 6;
  long long obase = (long long)head * TT * HSS + (long long)(qc * 64 + rr) * HSS;
#pragma unroll
  for (int c = 0; c < 4; c++) {
    __syncthreads();
    Osc[w][r][0] = o[c * 4 + 0];
    Osc[w][r][1] = o[c * 4 + 1];
    Osc[w][r][2] = o[c * 4 + 2];
    Osc[w][r][3] = o[c * 4 + 3];
    if (c == 0) { Ms[w][r] = m; Ls[w][r] = l; }
    __syncthreads();
    float m0 = Ms[0][rr], m1 = Ms[1][rr], m2 = Ms[2][rr], m3 = Ms[3][rr];
    float M = fmaxf(fmaxf(m0, m1), fmaxf(m2, m3));
    float s0 = __expf(m0 - M), s1 = __expf(m1 - M);
    float s2 = __expf(m2 - M), s3 = __expf(m3 - M);
    float L = s0 * Ls[0][rr] + s1 * Ls[1][rr] + s2 * Ls[2][rr] + s3 * Ls[3][rr];
    float rl = 1.f / L;
    float4 a0 = Osc[0][rr][ii], a1 = Osc[1][rr][ii];
    float4 a2 = Osc[2][rr][ii], a3 = Osc[3][rr][ii];
    float4 res;
    res.x = (s0 * a0.x + s1 * a1.x + s2 * a2.x + s3 * a3.x) * rl;
    res.y = (s0 * a0.y + s1 * a1.y + s2 * a2.y + s3 * a3.y) * rl;
    res.z = (s0 * a0.z + s1 * a1.z + s2 * a2.z + s3 * a3.z) * rl;
    res.w = (s0 * a0.w + s1 * a1.w + s2 * a2.w + s3 * a3.w) * rl;
    long long oaddr = obase + c * 16 + ii * 4;
    *(float4*)(attn + oaddr) = res;
    if (ap) {
      float rv[4] = {res.x, res.y, res.z, res.w};
      short p0[4], p1[4], p2[4];
#pragma unroll
      for (int j = 0; j < 4; j++) split3(rv[j], p0[j], p1[j], p2[j]);
      *(short4*)(ap + oaddr)                    = make_short4(p0[0], p0[1], p0[2], p0[3]);
      *(short4*)(ap + (size_t)NN*DD + oaddr)    = make_short4(p1[0], p1[1], p1[2], p1[3]);
      *(short4*)(ap + (size_t)2*NN*DD + oaddr)  = make_short4(p2[0], p2[1], p2[2], p2[3]);
    }
  }
}

// ---------------- router ----------------
__global__ __launch_bounds__(64) void router_kernel(
    const float* __restrict__ y, const float* __restrict__ rw, const float* __restrict__ rb,
    const float* __restrict__ nw, const float* __restrict__ nb, const float* __restrict__ noise,
    int* __restrict__ slot_e, float* __restrict__ slot_g) {
  int n = blockIdx.x;
  int lane = threadIdx.x;
  double accr[EE], accn[EE];
#pragma unroll
  for (int e = 0; e < EE; e++) { accr[e] = 0.0; accn[e] = 0.0; }
  for (int j = 0; j < 16; j++) {
    float xv = y[(long long)n * DD + j * 64 + lane];
#pragma unroll
    for (int e = 0; e < EE; e++) {
      accr[e] += (double)xv * (double)rw[e * DD + j * 64 + lane];
      accn[e] += (double)xv * (double)nw[e * DD + j * 64 + lane];
    }
  }
#pragma unroll
  for (int e = 0; e < EE; e++) {
    for (int off = 32; off > 0; off >>= 1) {
      accr[e] += __shfl_down(accr[e], off);
      accn[e] += __shfl_down(accn[e], off);
    }
  }
  if (lane == 0) {
    float noisy[EE];
#pragma unroll
    for (int e = 0; e < EE; e++) {
      float lg = (float)accr[e] + rb[e];
      float nl = (float)accn[e] + nb[e];
      float sp = (nl > 0.f) ? (nl + log1pf(expf(-nl))) : log1pf(expf(nl));
      noisy[e] = lg + noise[n * EE + e] * sp;
    }
    int i0 = 0;
#pragma unroll
    for (int e = 1; e < EE; e++) if (noisy[e] > noisy[i0]) i0 = e;
    int i1 = -1;
#pragma unroll
    for (int e = 0; e < EE; e++) {
      if (e == i0) continue;
      if (i1 < 0 || noisy[e] > noisy[i1]) i1 = e;
    }
    float v0 = noisy[i0], v1 = noisy[i1];
    float e1 = __expf(v1 - v0);
    float inv = 1.f / (1.f + e1);
    slot_e[2 * n] = i0; slot_e[2 * n + 1] = i1;
    slot_g[2 * n] = inv; slot_g[2 * n + 1] = e1 * inv;
  }
}

// ---------------- deterministic rank scan ----------------
__global__ __launch_bounds__(256) void scan_kernel(const int* __restrict__ slot_e,
                                                   int* __restrict__ slot_pos) {
  __shared__ int cnt[256 * EE];
  int tid = threadIdx.x;
  int base = tid * 16;
  int c[EE];
#pragma unroll
  for (int e = 0; e < EE; e++) c[e] = 0;
  int loc[16];
  for (int i = 0; i < 16; i++) {
    int e = slot_e[base + i];
    loc[i] = e;
    c[e]++;
  }
#pragma unroll
  for (int e = 0; e < EE; e++) cnt[tid * EE + e] = c[e];
  __syncthreads();
  if (tid < EE) {
    int run = 0;
    for (int t2 = 0; t2 < 256; t2++) {
      int v = cnt[t2 * EE + tid];
      cnt[t2 * EE + tid] = run;
      run += v;
    }
  }
  __syncthreads();
  int run[EE];
#pragma unroll
  for (int e = 0; e < EE; e++) run[e] = cnt[tid * EE + e];
  for (int i = 0; i < 16; i++) {
    int e = loc[i];
    int r = run[e]++;
    slot_pos[base + i] = (r < CAPP) ? (e * CAPP + r) : -1;
  }
}

// ---------------- dispatch (fp32 fallback) ----------------
__global__ __launch_bounds__(256) void dispatch_kernel(const float* __restrict__ y,
                                                       const int* __restrict__ slot_pos,
                                                       float* __restrict__ disp) {
  int i = blockIdx.x;
  int pos = slot_pos[i];
  if (pos < 0) return;
  int tok = i >> 1;
  ((float4*)(disp + (long long)pos * DD))[threadIdx.x] =
      ((const float4*)(y + (long long)tok * DD))[threadIdx.x];
}

// ---------------- dispatch (bf16x3 planes) ----------------
__global__ __launch_bounds__(256) void dispatch_planes_kernel(const short* __restrict__ yp,
                                                              const int* __restrict__ slot_pos,
                                                              short* __restrict__ dp) {
  int i = blockIdx.x;
  int pos = slot_pos[i];
  if (pos < 0) return;
  int tok = i >> 1;
#pragma unroll
  for (int p = 0; p < 3; p++) {
    short4 v = ((const short4*)(yp + (size_t)p * NN * DD + (size_t)tok * DD))[threadIdx.x];
    ((short4*)(dp + (size_t)p * EE * CAPP * DD + (size_t)pos * DD))[threadIdx.x] = v;
  }
}

// ---------------- combine ----------------
__global__ __launch_bounds__(256) void combine_kernel(float* __restrict__ x,
                                                      const float* __restrict__ eo,
                                                      const int* __restrict__ slot_pos,
                                                      const float* __restrict__ slot_g) {
  int n = blockIdx.x, tid = threadIdx.x;
  int p0 = slot_pos[2 * n], p1 = slot_pos[2 * n + 1];
  float g0 = slot_g[2 * n], g1 = slot_g[2 * n + 1];
  float4 v = ((float4*)(x + (long long)n * DD))[tid];
  if (p0 >= 0) {
    float4 e0 = ((const float4*)(eo + (long long)p0 * DD))[tid];
    v.x = fmaf(g0, e0.x, v.x); v.y = fmaf(g0, e0.y, v.y);
    v.z = fmaf(g0, e0.z, v.z); v.w = fmaf(g0, e0.w, v.w);
  }
  if (p1 >= 0) {
    float4 e1 = ((const float4*)(eo + (long long)p1 * DD))[tid];
    v.x = fmaf(g1, e1.x, v.x); v.y = fmaf(g1, e1.y, v.y);
    v.z = fmaf(g1, e1.z, v.z); v.w = fmaf(g1, e1.w, v.w);
  }
  ((float4*)(x + (long long)n * DD))[tid] = v;
}

extern "C" void kernel_launch(void* const* d_in, const int* in_sizes, int n_in,
                              void* d_out, int out_size, void* d_ws, size_t ws_size,
                              hipStream_t stream) {
  const int* input_ids = (const int*)d_in[0];
  const float* noise = (const float*)d_in[1];
  const float* tok_emb = (const float*)d_in[2];
  const float* pos_emb = (const float*)d_in[3];
  const float* ln1_w = (const float*)d_in[4];
  const float* ln1_b = (const float*)d_in[5];
  const float* ln2_w = (const float*)d_in[6];
  const float* ln2_b = (const float*)d_in[7];
  const float* qkv_w = (const float*)d_in[8];
  const float* out_w = (const float*)d_in[9];
  const float* router_w = (const float*)d_in[10];
  const float* router_b = (const float*)d_in[11];
  const float* noise_w = (const float*)d_in[12];
  const float* noise_b = (const float*)d_in[13];
  const float* e_w1 = (const float*)d_in[14];
  const float* e_b1 = (const float*)d_in[15];
  const float* e_w2 = (const float*)d_in[16];
  const float* e_b2 = (const float*)d_in[17];
  const float* lnf_w = (const float*)d_in[18];
  const float* lnf_b = (const float*)d_in[19];
  float* out = (float*)d_out;

  // ---- workspace layout ----
  float* ws = (float*)d_ws;
  size_t off = 0;
  float* x = ws + off;       off += (size_t)NN * DD;
  float* y = ws + off;       off += (size_t)NN * DD;
  float* qkv = ws + off;     off += (size_t)NN * 3 * DD;
  float* eo = ws + off;      off += (size_t)EE * CAPP * DD;
  float* sintab = ws + off;  off += (size_t)TT * HALF;
  float* costab = ws + off;  off += (size_t)TT * HALF;
  float* attn32 = ws + off;  off += (size_t)NN * DD;
  int* slot_e = (int*)(ws + off);   off += NK;
  int* slot_pos = (int*)(ws + off); off += NK;
  float* slot_g = ws + off;  off += NK;
  size_t base_floats = off;
  // overlay region: fallback fp32 disp/hbuf  OR  mfma short planes
  float* disp32 = ws + off;
  float* hbuf32 = disp32 + (size_t)EE * CAPP * DD;
  size_t fb_need = (base_floats + (size_t)EE * CAPP * DD + (size_t)EE * CAPP * DFF) * 4;

  short* sp = (short*)(ws + base_floats);
  short* y_p = sp;                                   sp += (size_t)3 * NN * DD;
  short* attn_p = sp;                                sp += (size_t)3 * NN * DD;
  short* disp_p = sp;                                sp += (size_t)3 * EE * CAPP * DD;
  short* hbuf_p = sp;                                sp += (size_t)3 * EE * CAPP * DFF;
  short* qkvw_p = sp;                                sp += (size_t)3 * LL * 3 * DD * DD;
  short* outw_p = sp;                                sp += (size_t)3 * LL * DD * DD;
  short* ew_p = sp;                                  sp += (size_t)3 * EE * DFF * DD;
  size_t mfma_need = (size_t)((char*)sp - (char*)d_ws);
  bool use_mfma = (ws_size >= mfma_need);
  (void)fb_need;

  embed_kernel<<<TT, 256, 0, stream>>>(input_ids, tok_emb, pos_emb, x);
  sincos_kernel<<<(TT * HALF) / 256, 256, 0, stream>>>(sintab, costab);

  if (use_mfma) {
    long long nq = (long long)LL * 3 * DD * DD;
    long long no = (long long)LL * DD * DD;
    convert_kernel<<<(int)(nq / 2048), 256, 0, stream>>>(qkv_w, qkvw_p, nq);
    convert_kernel<<<(int)(no / 2048), 256, 0, stream>>>(out_w, outw_p, no);
    long long ne = (long long)EE * DFF * DD;

    for (int l = 0; l < LL; l++) {
      int fastf = (l == LL - 1) ? 8 : 0;
      ln_kernel<<<NN, 256, 0, stream>>>(x, y, y_p, ln1_w + l * DD, ln1_b + l * DD);
      gemm_mfma<<<dim3(3 * DD / 128, NN / 128, 1), 256, 0, stream>>>(
          y_p, qkvw_p + (size_t)l * 3 * DD * DD, nullptr, nullptr, qkv,
          NN, 3 * DD, DD, 0, 0, 0, 0, 0,
          (long long)NN * DD, (long long)LL * 3 * DD * DD, 0);
      rope_kernel<<<TT, 256, 0, stream>>>(qkv, sintab, costab);
      attn_kernel<<<512, 256, 0, stream>>>(qkv, attn32, attn_p);
      gemm_mfma<<<dim3(DD / 128, NN / 128, 1), 256, 0, stream>>>(
          attn_p, outw_p + (size_t)l * DD * DD, nullptr, x, x,
          NN, DD, DD, 4, 0, 0, 0, 0,
          (long long)NN * DD, (long long)LL * DD * DD, 0);
      ln_kernel<<<NN, 256, 0, stream>>>(x, y, y_p, ln2_w + l * DD, ln2_b + l * DD);
      router_kernel<<<NN, 64, 0, stream>>>(
          y, router_w + (size_t)l * EE * DD, router_b + l * EE,
          noise_w + (size_t)l * EE * DD, noise_b + l * EE,
          noise + (size_t)l * NN * EE, slot_e, slot_g);
      scan_kernel<<<1, 256, 0, stream>>>(slot_e, slot_pos);
      dispatch_planes_kernel<<<NK, 256, 0, stream>>>(y_p, slot_pos, disp_p);
      convert_kernel<<<(int)(ne / 2048), 256, 0, stream>>>(e_w1 + (size_t)l * ne, ew_p, ne);
      gemm_mfma<<<dim3(DFF / 128, CAPP / 128, EE), 256, 0, stream>>>(
          disp_p, ew_p, e_b1 + (size_t)l * EE * DFF, nullptr, hbuf_p,
          CAPP, DFF, DD, 1 | 2 | 16 | fastf,
          (long long)CAPP * DD, (long long)DFF * DD, DFF, (long long)CAPP * DFF,
          (long long)EE * CAPP * DD, (long long)EE * DFF * DD, (long long)EE * CAPP * DFF);
      convert_kernel<<<(int)(ne / 2048), 256, 0, stream>>>(e_w2 + (size_t)l * ne, ew_p, ne);
      gemm_mfma<<<dim3(DD / 128, CAPP / 128, EE), 256, 0, stream>>>(
          hbuf_p, ew_p, e_b2 + (size_t)l * EE * DD, nullptr, eo,
          CAPP, DD, DFF, 1 | fastf,
          (long long)CAPP * DFF, (long long)DD * DFF, DD, (long long)CAPP * DD,
          (long long)EE * CAPP * DFF, (long long)EE * DD * DFF, 0);
      combine_kernel<<<NN, 256, 0, stream>>>(x, eo, slot_pos, slot_g);
    }
  } else {
    for (int l = 0; l < LL; l++) {
      ln_kernel<<<NN, 256, 0, stream>>>(x, y, nullptr, ln1_w + l * DD, ln1_b + l * DD);
      gemm_kernel<<<dim3(3 * DD / 128, NN / 128, 1), 256, 0, stream>>>(
          y, qkv_w + (size_t)l * 3 * DD * DD, nullptr, nullptr, qkv,
          NN, 3 * DD, DD, 0, 0, 0, 0, 0);
      rope_kernel<<<TT, 256, 0, stream>>>(qkv, sintab, costab);
      attn_kernel<<<512, 256, 0, stream>>>(qkv, attn32, nullptr);
      gemm_kernel<<<dim3(DD / 128, NN / 128, 1), 256, 0, stream>>>(
          attn32, out_w + (size_t)l * DD * DD, nullptr, x, x,
          NN, DD, DD, 4, 0, 0, 0, 0);
      ln_kernel<<<NN, 256, 0, stream>>>(x, y, nullptr, ln2_w + l * DD, ln2_b + l * DD);
      router_kernel<<<NN, 64, 0, stream>>>(
          y, router_w + (size_t)l * EE * DD, router_b + l * EE,
          noise_w + (size_t)l * EE * DD, noise_b + l * EE,
          noise + (size_t)l * NN * EE, slot_e, slot_g);
      scan_kernel<<<1, 256, 0, stream>>>(slot_e, slot_pos);
      dispatch_kernel<<<NK, 256, 0, stream>>>(y, slot_pos, disp32);
      gemm_kernel<<<dim3(DFF / 128, CAPP / 128, EE), 256, 0, stream>>>(
          disp32, e_w1 + (size_t)l * EE * DFF * DD, e_b1 + (size_t)l * EE * DFF, nullptr, hbuf32,
          CAPP, DFF, DD, 3,
          (long long)CAPP * DD, (long long)DFF * DD, DFF, (long long)CAPP * DFF);
      gemm_kernel<<<dim3(DD / 128, CAPP / 128, EE), 256, 0, stream>>>(
          hbuf32, e_w2 + (size_t)l * EE * DD * DFF, e_b2 + (size_t)l * EE * DD, nullptr, eo,
          CAPP, DD, DFF, 1,
          (long long)CAPP * DFF, (long long)DD * DFF, DD, (long long)CAPP * DD);
      combine_kernel<<<NN, 256, 0, stream>>>(x, eo, slot_pos, slot_g);
    }
  }
  ln_kernel<<<NN, 256, 0, stream>>>(x, out, nullptr, lnf_w, lnf_b);
  (void)in_sizes; (void)n_in; (void)out_size; (void)ws_size;
}